// Round 1
// baseline (90.015 us; speedup 1.0000x reference)
//
#include <hip/hip_runtime.h>
#include <math.h>

// [log e4, log e5] of {exp(x_i)} per row via power sums + Newton's identities.
//
// v2: split into (A) a pure streaming power-sum kernel and (B) a tiny
// fully-parallel f64 Newton+log epilogue kernel.
// Rationale: the fused kernel inlined two software f64 log() calls + the f64
// Newton chain into the streaming kernel, inflating VGPRs (occupancy) and
// holding each block's slot through a long serial lane-0 tail. Kernel A now
// contains no f64 and no transcendental epilogue: blocks retire right after
// the 5-float LDS combine, keeping the HBM pipe continuously fed.
//
// Accuracy: full-row sums handed off as f32 (~1e-6 rel); after Newton's
// (documented >=1e3 dominance, no catastrophic cancellation) this is ~1e-3
// abs on the log outputs vs the 0.86 threshold.

__device__ __forceinline__ void accum4(float4 v, float& p1, float& p2,
                                       float& p3, float& p4, float& p5) {
    float e0 = __expf(v.x), e1 = __expf(v.y), e2 = __expf(v.z), e3 = __expf(v.w);
    float s0 = e0 * e0, s1 = e1 * e1, s2 = e2 * e2, s3 = e3 * e3;
    float t0 = s0 * s0, t1 = s1 * s1, t2 = s2 * s2, t3 = s3 * s3;
    p1 += (e0 + e1) + (e2 + e3);
    p2 += (s0 + s1) + (s2 + s3);
    p3 += (s0 * e0 + s1 * e1) + (s2 * e2 + s3 * e3);
    p4 += (t0 + t1) + (t2 + t3);
    p5 += (t0 * e0 + t1 * e1) + (t2 * e2 + t3 * e3);
}

// Kernel A: one block (256 thr) per row; 8192-col path fully unrolled so all
// 8 float4 loads per thread are issued before any dependent use (max MLP).
// Writes the 5 power sums (f32) for its row to sums[row*5 + 0..4].
__global__ __launch_bounds__(256, 4)
void psum_kernel(const float* __restrict__ x, float* __restrict__ sums,
                 int n_cols) {
    const int row = blockIdx.x;
    const int tid = threadIdx.x;
    const float4* __restrict__ xr =
        reinterpret_cast<const float4*>(x + (size_t)row * (size_t)n_cols);
    const int nvec = n_cols >> 2;

    float p1 = 0.f, p2 = 0.f, p3 = 0.f, p4 = 0.f, p5 = 0.f;

    if (n_cols == 8192) {
        // 2048 float4 / 256 threads = 8 per thread. Load all 8 first so the
        // wave has 8 outstanding global loads (hides ~900-cyc HBM latency).
        float4 v[8];
        #pragma unroll
        for (int j = 0; j < 8; ++j) v[j] = xr[tid + (j << 8)];
        #pragma unroll
        for (int j = 0; j < 8; ++j) accum4(v[j], p1, p2, p3, p4, p5);
    } else {
        for (int i = tid; i < nvec; i += 256) accum4(xr[i], p1, p2, p3, p4, p5);
    }

    // Wave(64)-wide f32 butterfly reduction.
    #pragma unroll
    for (int off = 32; off > 0; off >>= 1) {
        p1 += __shfl_down(p1, off);
        p2 += __shfl_down(p2, off);
        p3 += __shfl_down(p3, off);
        p4 += __shfl_down(p4, off);
        p5 += __shfl_down(p5, off);
    }

    __shared__ float sred[4][5];
    const int wave = tid >> 6;
    if ((tid & 63) == 0) {
        sred[wave][0] = p1; sred[wave][1] = p2; sred[wave][2] = p3;
        sred[wave][3] = p4; sred[wave][4] = p5;
    }
    __syncthreads();

    if (tid < 5) {
        float t = (sred[0][tid] + sred[1][tid]) + (sred[2][tid] + sred[3][tid]);
        sums[(size_t)row * 5 + tid] = t;
    }
}

// Kernel B: one thread per row. All the f64 (Newton chain + two software
// f64 logs) lives here, fully parallel across 2048 threads, so its register
// and latency cost never touches the streaming kernel.
__global__ __launch_bounds__(256)
void newton_kernel(const float* __restrict__ sums, float* __restrict__ out,
                   int n_rows) {
    const int r = blockIdx.x * 256 + threadIdx.x;
    if (r >= n_rows) return;
    const float* s = sums + (size_t)r * 5;
    double P1 = (double)s[0], P2 = (double)s[1], P3 = (double)s[2],
           P4 = (double)s[3], P5 = (double)s[4];
    // Newton's identities in f64 (no catastrophic cancellation: the
    // e_{j-1}*P1 term dominates corrections by >=1e3 for this input).
    double e1 = P1;
    double e2 = (e1 * P1 - P2) * 0.5;
    double e3 = (e2 * P1 - e1 * P2 + P3) * (1.0 / 3.0);
    double e4 = (e3 * P1 - e2 * P2 + e1 * P3 - P4) * 0.25;
    double e5 = (e4 * P1 - e3 * P2 + e2 * P3 - e1 * P4 + P5) * 0.2;
    out[r]          = (float)log(e4);
    out[n_rows + r] = (float)log(e5);
}

extern "C" void kernel_launch(void* const* d_in, const int* in_sizes, int n_in,
                              void* d_out, int out_size, void* d_ws, size_t ws_size,
                              hipStream_t stream) {
    const float* x = (const float*)d_in[0];
    float* out = (float*)d_out;
    const int n_rows = out_size / 2;          // 2048
    const int n_cols = in_sizes[0] / n_rows;  // 8192
    float* sums = (float*)d_ws;               // n_rows*5 floats = 40 KB << ws

    psum_kernel<<<n_rows, 256, 0, stream>>>(x, sums, n_cols);
    newton_kernel<<<(n_rows + 255) / 256, 256, 0, stream>>>(sums, out, n_rows);
}